// Round 13
// baseline (20030.640 us; speedup 1.0000x reference)
//
#include <hip/hip_runtime.h>
#include <math.h>

#define BATCH 512
#define SEQ   200
#define DIN   64
#define HID   512
#define GW    2048   // 4*HID
#define EPS   1e-5f
#define NREG  4      // G regions: ih0 | hh0 | ih1 | hh1
#define NBLK_MM 256

typedef _Float16 half_t;
typedef half_t half8 __attribute__((ext_vector_type(8)));
typedef float  f32x4  __attribute__((ext_vector_type(4)));
typedef float  f32x16 __attribute__((ext_vector_type(16)));

#define WN0 (2048*64)     // W_ih0 elems
#define WN1 (2048*512)    // W_hh0 / W_ih1 / W_hh1 elems
#define WTOT (WN0 + 3*WN1)
#define XFRAG ((size_t)SEQ*16*4*512)   // per-plane xsplit elems (frag-major)

__device__ __forceinline__ float sigf(float x){ return 1.0f/(1.0f+expf(-x)); }

// async global->LDS, 16B per lane; LDS dest = wave-uniform base + lane*16 (HW)
__device__ __forceinline__ void gload16(const half_t* g, half_t* l){
  __builtin_amdgcn_global_load_lds(
      (const __attribute__((address_space(1))) void*)g,
      (__attribute__((address_space(3))) void*)l, 16, 0, 0);
}

__device__ __forceinline__ void barf(){
  asm volatile("" ::: "memory");
  __builtin_amdgcn_s_barrier();
  asm volatile("" ::: "memory");
}

// wave-level (64-lane) butterfly all-reduce of 2 values
__device__ __forceinline__ void wred2(float&a,float&b){
  #pragma unroll
  for(int o=32;o;o>>=1){ a+=__shfl_xor(a,o); b+=__shfl_xor(b,o); }
}
__device__ __forceinline__ void wred4(float&a,float&b,float&c,float&d){
  #pragma unroll
  for(int o=32;o;o>>=1){
    a+=__shfl_xor(a,o); b+=__shfl_xor(b,o);
    c+=__shfl_xor(c,o); d+=__shfl_xor(d,o);
  }
}

// Reduce 4 values across a 256-thread block. red must be float[16] shared.
__device__ __forceinline__ void block_reduce4(float&a,float&b,float&c,float&d,float* red){
  #pragma unroll
  for(int o=32;o;o>>=1){
    a+=__shfl_down(a,o); b+=__shfl_down(b,o);
    c+=__shfl_down(c,o); d+=__shfl_down(d,o);
  }
  const int lane = threadIdx.x & 63, wid = threadIdx.x>>6;
  if(lane==0){ red[wid*4+0]=a; red[wid*4+1]=b; red[wid*4+2]=c; red[wid*4+3]=d; }
  __syncthreads();
  a = red[0]+red[4]+red[8]+red[12];
  b = red[1]+red[5]+red[9]+red[13];
  c = red[2]+red[6]+red[10]+red[14];
  d = red[3]+red[7]+red[11]+red[15];
  __syncthreads();
}

// Per-batch-row stats for ln1 (joint LayerNorm over (S,D) = 12800 elems)
__global__ __launch_bounds__(256) void ln1_stats(const float* __restrict__ x,
                                                 float* __restrict__ mu,
                                                 float* __restrict__ rs){
  const int b = blockIdx.x;
  const float* xb = x + (size_t)b*SEQ*DIN;
  float s=0, ss=0, d=0, e=0;
  for (int i=threadIdx.x; i<SEQ*DIN; i+=256){ float v=xb[i]; s+=v; ss+=v*v; }
  __shared__ float red[16];
  block_reduce4(s,ss,d,e,red);
  if (threadIdx.x==0){
    float m = s*(1.0f/(SEQ*DIN));
    mu[b] = m;
    rs[b] = rsqrtf(ss*(1.0f/(SEQ*DIN)) - m*m + EPS);
  }
}

// Split the 4 weight matrices into fp16 hi/lo in FRAGMENT-MAJOR packed layout.
//   idx = ((p*C + c)*4 + nf*2 + ks)*512 + l*8 + j
//   n = p*64 + nf*32 + (l&31);  k = c*32 + ks*16 + (l>>5)*8 + j
__global__ __launch_bounds__(256) void wsplit(
    const float* __restrict__ W0, const float* __restrict__ W1,
    const float* __restrict__ W2, const float* __restrict__ W3,
    half_t* __restrict__ Wh, half_t* __restrict__ Wl)
{
  int i = blockIdx.x*256 + threadIdx.x;
  if (i >= WTOT) return;
  const float* src; int off, Kd;
  if (i < WN0){ src=W0; off=i; Kd=DIN; }
  else {
    int r = (i-WN0)/WN1; off = (i-WN0) - r*WN1; Kd=HID;
    src = (r==0)?W1:((r==1)?W2:W3);
  }
  const int C = Kd>>5;            // 2 or 16 (pow2)
  int j  = off & 7;
  int l  = (off>>3) & 63;
  int ks = (off>>9) & 1;
  int nf = (off>>10) & 1;
  int pc = off>>11;
  int c  = pc & (C-1);
  int p  = pc >> (Kd==DIN ? 1 : 4);
  int n  = p*64 + nf*32 + (l&31);
  int k  = c*32 + ks*16 + (l>>5)*8 + j;
  float v = src[(size_t)n*Kd + k];
  half_t h = (half_t)v;
  Wh[i] = h;
  Wl[i] = (half_t)(v - (float)h);
}

// Precompute ln1(x) fp16 hi/lo splits for ALL t in MFMA-A-fragment layout:
//   idx = ((t*16 + mch)*4 + c)*512 + l*8 + j
//   b = mch*32 + (l&31);  k = c*16 + (l>>5)*8 + j
__global__ __launch_bounds__(256) void xprep(
    const float* __restrict__ x, const float* __restrict__ g1, const float* __restrict__ b1,
    const float* __restrict__ mu, const float* __restrict__ rs,
    half_t* __restrict__ xh, half_t* __restrict__ xl)
{
  size_t i = (size_t)blockIdx.x*256 + threadIdx.x;
  if (i >= XFRAG) return;
  int j   = (int)(i & 7);
  int l   = (int)((i>>3) & 63);
  int c   = (int)((i>>9) & 3);
  int mch = (int)((i>>11) & 15);
  int t   = (int)(i>>15);
  int b   = mch*32 + (l&31);
  int k   = c*16 + ((l>>5)<<3) + j;
  float v = (x[(size_t)b*(SEQ*DIN) + t*DIN + k] - mu[b]) * rs[b]
            * g1[t*DIN+k] + b1[t*DIN+k];
  half_t h = (half_t)v;
  xh[i] = h;
  xl[i] = (half_t)(v - (float)h);
}

// ---- fused per-tick kernel: mm phase -> device flag-barrier -> upd phase ----
// grid 256 x 256 thr (1 block/CU guaranteed resident -> spin is deadlock-free).
// Phase 1 (mm): R10's best-measured LDS-staged loop (32-k steps, dbuf,
//   counted vmcnt(8)); block = 128m x 128n (2x2 waves, wave 64x64).
// Barrier: nt G stores -> vmcnt(0) -> threadfence -> atomicAdd ctr[t] -> spin 256.
// Phase 2 (upd): 4 units/block, ONE PER WAVE (shfl reductions, no block syncs);
//   unit = w*256 + bi: layer = unit>>9, row = unit&511. G staged in dead mm LDS.
__global__ __launch_bounds__(256, 1) void tick_fused(
    const half_t* __restrict__ xh, const half_t* __restrict__ xl,
    half_t* __restrict__ h0fh, half_t* __restrict__ h0fl,
    half_t* __restrict__ h1fh, half_t* __restrict__ h1fl,
    const half_t* __restrict__ Wh, const half_t* __restrict__ Wl,
    float* __restrict__ G, int* __restrict__ ctr,
    const float* __restrict__ b_ih0, const float* __restrict__ b_hh0,
    const float* __restrict__ b_ih1, const float* __restrict__ b_hh1,
    const float* __restrict__ g_ih0, const float* __restrict__ be_ih0,
    const float* __restrict__ g_hh0, const float* __restrict__ be_hh0,
    const float* __restrict__ g_ho0, const float* __restrict__ be_ho0,
    const float* __restrict__ g_ih1, const float* __restrict__ be_ih1,
    const float* __restrict__ g_hh1, const float* __restrict__ be_hh1,
    const float* __restrict__ g_ho1, const float* __restrict__ be_ho1,
    float* __restrict__ c0, float* __restrict__ c1, float* __restrict__ h1,
    int t)
{
  __shared__ __align__(16) half_t sbuf[2*16384];   // 64 KB: mm dbuf, then upd GS

  const int bi   = blockIdx.x;
  const int tid  = threadIdx.x;
  const int lane = tid & 63;
  const int w    = tid >> 6;
  const int ln31 = lane & 31;

  // ================= phase 1: mm =================
  {
    const int slot = bi >> 3;
    const int z    = slot & 3;             // region 0..3
    const int y    = (slot >> 2) & 3;      // m-group 0..3
    const int x    = (bi & 7)*2 + (slot >> 4);  // n-group 0..15

    const int mch0 = y*4 + (w>>1)*2;
    const int p    = x*2 + (w&1);
    const int wn0  = p*64;

    const half_t* BHb = Wh + WN0; const half_t* BLb = Wl + WN0;
    int Kd = HID;
    if (z==0){ BHb=Wh; BLb=Wl; Kd=DIN; }
    else if (z==2){ BHb=Wh+WN0+WN1; BLb=Wl+WN0+WN1; }
    else if (z==3){ BHb=Wh+WN0+2*WN1; BLb=Wl+WN0+2*WN1; }

    const int C32 = Kd >> 5;
    const int C16 = Kd >> 4;

    const int tq = (t < SEQ) ? t : (SEQ-1);   // t==200 region0 result unused
    const half_t *AHb, *ALb;
    if (z==0){ AHb = xh + (size_t)tq*32768; ALb = xl + (size_t)tq*32768; }
    else if (z==3){ AHb = h1fh; ALb = h1fl; }
    else { AHb = h0fh; ALb = h0fl; }

    // staging: waves 0,1 -> A (mch pairs); waves 2,3 -> B (one panel each)
    auto stage = [&](int s){
      half_t* dst = sbuf + (size_t)(s&1)*16384;
      if (w < 2){
        #pragma unroll
        for (int q=0;q<2;q++){
          const int mci = w*2+q;
          const size_t abase = ((size_t)(y*4+mci)*C16 + 2*s)*512;
          #pragma unroll
          for (int pl=0;pl<2;pl++){
            const half_t* src = (pl? ALb : AHb) + abase + lane*8;
            half_t* d = dst + (mci*2+pl)*1024;
            gload16(src,       d);
            gload16(src + 512, d + 512);
          }
        }
      } else {
        const int ph = w-2;
        const size_t bbase = ((size_t)(x*2+ph)*C32 + s)*2048;
        #pragma unroll
        for (int pl=0;pl<2;pl++){
          const half_t* src = (pl? BLb : BHb) + bbase + lane*8;
          half_t* d = dst + 8192 + (ph*2+pl)*2048;
          #pragma unroll
          for (int i=0;i<4;i++)
            gload16(src + i*512, d + i*512);
        }
      }
    };

    f32x16 acc00 = {0.f,0.f,0.f,0.f,0.f,0.f,0.f,0.f,0.f,0.f,0.f,0.f,0.f,0.f,0.f,0.f};
    f32x16 acc01 = acc00, acc10 = acc00, acc11 = acc00;

    const int mh = w>>1, pw = w&1;
    auto compute = [&](const half_t* buf, int ks){
      const half_t* Ab = buf;
      const half_t* Bb = buf + 8192;
      half8 ah0 = *(const half8*)(Ab + ((mh*2+0)*2+0)*1024 + ks*512 + lane*8);
      half8 al0 = *(const half8*)(Ab + ((mh*2+0)*2+1)*1024 + ks*512 + lane*8);
      half8 ah1 = *(const half8*)(Ab + ((mh*2+1)*2+0)*1024 + ks*512 + lane*8);
      half8 al1 = *(const half8*)(Ab + ((mh*2+1)*2+1)*1024 + ks*512 + lane*8);
      half8 bh0 = *(const half8*)(Bb + ((pw*2+0)*4 + 0 + ks)*512 + lane*8);
      half8 bh1 = *(const half8*)(Bb + ((pw*2+0)*4 + 2 + ks)*512 + lane*8);
      half8 bl0 = *(const half8*)(Bb + ((pw*2+1)*4 + 0 + ks)*512 + lane*8);
      half8 bl1 = *(const half8*)(Bb + ((pw*2+1)*4 + 2 + ks)*512 + lane*8);
      acc00 = __builtin_amdgcn_mfma_f32_32x32x16_f16(ah0, bh0, acc00, 0,0,0);
      acc01 = __builtin_amdgcn_mfma_f32_32x32x16_f16(ah0, bh1, acc01, 0,0,0);
      acc10 = __builtin_amdgcn_mfma_f32_32x32x16_f16(ah1, bh0, acc10, 0,0,0);
      acc11 = __builtin_amdgcn_mfma_f32_32x32x16_f16(ah1, bh1, acc11, 0,0,0);
      acc00 = __builtin_amdgcn_mfma_f32_32x32x16_f16(al0, bh0, acc00, 0,0,0);
      acc01 = __builtin_amdgcn_mfma_f32_32x32x16_f16(al0, bh1, acc01, 0,0,0);
      acc10 = __builtin_amdgcn_mfma_f32_32x32x16_f16(al1, bh0, acc10, 0,0,0);
      acc11 = __builtin_amdgcn_mfma_f32_32x32x16_f16(al1, bh1, acc11, 0,0,0);
      acc00 = __builtin_amdgcn_mfma_f32_32x32x16_f16(ah0, bl0, acc00, 0,0,0);
      acc01 = __builtin_amdgcn_mfma_f32_32x32x16_f16(ah0, bl1, acc01, 0,0,0);
      acc10 = __builtin_amdgcn_mfma_f32_32x32x16_f16(ah1, bl0, acc10, 0,0,0);
      acc11 = __builtin_amdgcn_mfma_f32_32x32x16_f16(ah1, bl1, acc11, 0,0,0);
    };

    stage(0);
    for (int s=0; s<C32; ++s){
      if (s+1 < C32){
        stage(s+1);
        asm volatile("s_waitcnt vmcnt(8)" ::: "memory");  // retire step-s, keep s+1 in flight
      } else {
        asm volatile("s_waitcnt vmcnt(0)" ::: "memory");
      }
      __builtin_amdgcn_sched_barrier(0);
      barf();
      const half_t* buf = sbuf + (size_t)(s&1)*16384;
      compute(buf, 0);
      compute(buf, 1);
      barf();
    }

    // C/D 32x32: col = lane&31, row = (reg&3)+8*(reg>>2)+4*(lane>>5)
    // Nontemporal: G bypasses L2 -> device-visible for phase 2 on any XCD.
    float* Gr = G + (size_t)z*BATCH*GW;
    const int rbase = (lane>>5)<<2;
    #pragma unroll
    for (int reg=0; reg<16; reg++){
      const int row = (reg&3) + ((reg>>2)<<3) + rbase;
      const int m0 = mch0*32 + row;
      const int m1 = m0 + 32;
      __builtin_nontemporal_store(acc00[reg], &Gr[(size_t)m0*GW + wn0 + ln31]);
      __builtin_nontemporal_store(acc01[reg], &Gr[(size_t)m0*GW + wn0 + 32 + ln31]);
      __builtin_nontemporal_store(acc10[reg], &Gr[(size_t)m1*GW + wn0 + ln31]);
      __builtin_nontemporal_store(acc11[reg], &Gr[(size_t)m1*GW + wn0 + 32 + ln31]);
    }
  }

  // ================= device flag-barrier =================
  asm volatile("s_waitcnt vmcnt(0)" ::: "memory");
  __threadfence();
  __syncthreads();
  if (tid==0){
    __hip_atomic_fetch_add(&ctr[t], 1, __ATOMIC_RELEASE, __HIP_MEMORY_SCOPE_AGENT);
    while (__hip_atomic_load(&ctr[t], __ATOMIC_ACQUIRE, __HIP_MEMORY_SCOPE_AGENT) < NBLK_MM)
      __builtin_amdgcn_s_sleep(4);
  }
  __syncthreads();   // releases all waves; also fences LDS reuse below

  // ================= phase 2: upd (one unit per wave) =================
  {
    const int unit  = w*256 + bi;       // 0..1023
    const int layer = unit >> 9;
    const int b     = unit & 511;
    const bool act  = (layer==0) ? (t < SEQ) : (t >= 1);
    if (!act) return;

    const float *GA,*GB,*bA,*bB,*gA,*beA,*gB,*beB,*gH,*bH;
    float *cs, *hs=nullptr; half_t *hfx,*lfx;
    const size_t rb = (size_t)b*GW;
    if (layer==0){
      GA = G + rb;
      GB = G + (size_t)1*BATCH*GW + rb;
      bA=b_ih0; bB=b_hh0;
      gA=g_ih0; beA=be_ih0; gB=g_hh0; beB=be_hh0; gH=g_ho0; bH=be_ho0;
      cs = c0 + b*HID; hfx = h0fh; lfx = h0fl;
    } else {
      GA = G + (size_t)2*BATCH*GW + rb;
      GB = G + (size_t)3*BATCH*GW + rb;
      bA=b_ih1; bB=b_hh1;
      gA=g_ih1; beA=be_ih1; gB=g_hh1; beB=be_hh1; gH=g_ho1; bH=be_ho1;
      cs = c1 + b*HID; hs = (t==SEQ) ? (h1 + b*HID) : nullptr; hfx = h1fh; lfx = h1fl;
    }

    float* GSw = ((float*)sbuf) + w*4096;   // 16 KB slice per wave: A[2048] B[2048]

    // pass 1: bias add, stage to LDS, LN stats (wave-local)
    float sa=0, ssa=0, sb=0, ssb=0;
    #pragma unroll
    for (int q=0;q<8;q++){
      const int i = q*256 + lane*4;
      f32x4 va = __builtin_nontemporal_load((const f32x4*)(GA+i));
      va += *(const f32x4*)(bA+i);
      *(f32x4*)(GSw+i) = va;
      f32x4 vb = __builtin_nontemporal_load((const f32x4*)(GB+i));
      vb += *(const f32x4*)(bB+i);
      *(f32x4*)(GSw+2048+i) = vb;
      #pragma unroll
      for (int q2=0;q2<4;q2++){
        sa += va[q2]; ssa += va[q2]*va[q2];
        sb += vb[q2]; ssb += vb[q2]*vb[q2];
      }
    }
    wred4(sa,ssa,sb,ssb);
    const float ma = sa*(1.0f/GW);
    const float ra = rsqrtf(ssa*(1.0f/GW) - ma*ma + EPS);
    const float mb2 = sb*(1.0f/GW);
    const float rb2 = rsqrtf(ssb*(1.0f/GW) - mb2*mb2 + EPS);

    // pass 2: gates, cell update, tanh(c) stats; u/o kept in registers
    float uu[8], oo[8];
    float s_u=0, s_uu=0;
    #pragma unroll
    for (int q=0;q<8;q++){
      const int j = q*64 + lane;
      float iv = ((GSw[j      ]-ma)*ra*gA[j      ]+beA[j      ]) + ((GSw[2048+j      ]-mb2)*rb2*gB[j      ]+beB[j      ]);
      float fv = ((GSw[j+  HID]-ma)*ra*gA[j+  HID]+beA[j+  HID]) + ((GSw[2048+j+  HID]-mb2)*rb2*gB[j+  HID]+beB[j+  HID]);
      float gv = ((GSw[j+2*HID]-ma)*ra*gA[j+2*HID]+beA[j+2*HID]) + ((GSw[2048+j+2*HID]-mb2)*rb2*gB[j+2*HID]+beB[j+2*HID]);
      float ov = ((GSw[j+3*HID]-ma)*ra*gA[j+3*HID]+beA[j+3*HID]) + ((GSw[2048+j+3*HID]-mb2)*rb2*gB[j+3*HID]+beB[j+3*HID]);
      float cn = sigf(fv)*cs[j] + sigf(iv)*tanhf(gv);
      cs[j] = cn;
      float u = tanhf(cn);
      uu[q] = u; oo[q] = sigf(ov);
      s_u += u; s_uu += u*u;
    }
    wred2(s_u,s_uu);
    const float mu_u = s_u*(1.0f/HID);
    const float ru   = rsqrtf(s_uu*(1.0f/HID) - mu_u*mu_u + EPS);

    // pass 3: h = sigmoid(o) * LN(tanh(c)); fp16 hi/lo in fragment layout
    const size_t fbase = ((size_t)(b>>5)*32)*512 + (size_t)(b&31)*8;
    #pragma unroll
    for (int q=0;q<8;q++){
      const int j = q*64 + lane;
      float v = oo[q] * ((uu[q]-mu_u)*ru*gH[j] + bH[j]);
      if (hs) hs[j] = v;
      half_t hv = (half_t)v;
      half_t lv = (half_t)(v - (float)hv);
      const size_t fi = fbase + (size_t)(j>>4)*512 + (size_t)((j>>3)&1)*256 + (j&7);
      hfx[fi] = hv;
      lfx[fi] = lv;
    }
  }
}

// Dense head: 512 -> 128 -> 64 -> 32 -> 1, one block per batch row
__global__ __launch_bounds__(256) void head_kernel(
    const float* __restrict__ h1,
    const float* __restrict__ Wd1, const float* __restrict__ bd1,
    const float* __restrict__ Wd2, const float* __restrict__ bd2,
    const float* __restrict__ Wd3, const float* __restrict__ bd3,
    const float* __restrict__ Wd4, const float* __restrict__ bd4,
    float* __restrict__ out)
{
  const int b = blockIdx.x;
  __shared__ float hv[HID];
  __shared__ float z1[128];
  __shared__ float z2[64];
  __shared__ float z3[32];
  const int tid = threadIdx.x;
  for (int i=tid;i<HID;i+=256) hv[i]=h1[(size_t)b*HID+i];
  __syncthreads();
  if (tid<128){
    float acc=bd1[tid]; const float* w=Wd1+(size_t)tid*512;
    for(int k=0;k<512;k++) acc+=hv[k]*w[k];
    z1[tid]=fmaxf(acc,0.f);
  }
  __syncthreads();
  if (tid<64){
    float acc=bd2[tid]; const float* w=Wd2+(size_t)tid*128;
    for(int k=0;k<128;k++) acc+=z1[k]*w[k];
    z2[tid]=fmaxf(acc,0.f);
  }
  __syncthreads();
  if (tid<32){
    float acc=bd3[tid]; const float* w=Wd3+(size_t)tid*64;
    for(int k=0;k<64;k++) acc+=z2[k]*w[k];
    z3[tid]=fmaxf(acc,0.f);
  }
  __syncthreads();
  if (tid==0){
    float acc=bd4[0];
    for(int k=0;k<32;k++) acc+=z3[k]*Wd4[k];
    out[b]=acc;
  }
}

extern "C" void kernel_launch(void* const* d_in, const int* in_sizes, int n_in,
                              void* d_out, int out_size, void* d_ws, size_t ws_size,
                              hipStream_t stream) {
  const float* x      = (const float*)d_in[0];
  const float* ln1_g  = (const float*)d_in[1];
  const float* ln1_b  = (const float*)d_in[2];
  const float* W_ih0  = (const float*)d_in[3];
  const float* b_ih0  = (const float*)d_in[4];
  const float* W_hh0  = (const float*)d_in[5];
  const float* b_hh0  = (const float*)d_in[6];
  const float* g_ih0  = (const float*)d_in[7];
  const float* be_ih0 = (const float*)d_in[8];
  const float* g_hh0  = (const float*)d_in[9];
  const float* be_hh0 = (const float*)d_in[10];
  const float* g_ho0  = (const float*)d_in[11];
  const float* be_ho0 = (const float*)d_in[12];
  const float* W_ih1  = (const float*)d_in[13];
  const float* b_ih1  = (const float*)d_in[14];
  const float* W_hh1  = (const float*)d_in[15];
  const float* b_hh1  = (const float*)d_in[16];
  const float* g_ih1  = (const float*)d_in[17];
  const float* be_ih1 = (const float*)d_in[18];
  const float* g_hh1  = (const float*)d_in[19];
  const float* be_hh1 = (const float*)d_in[20];
  const float* g_ho1  = (const float*)d_in[21];
  const float* be_ho1 = (const float*)d_in[22];
  const float* Wd1    = (const float*)d_in[23];
  const float* bd1    = (const float*)d_in[24];
  const float* Wd2    = (const float*)d_in[25];
  const float* bd2    = (const float*)d_in[26];
  const float* Wd3    = (const float*)d_in[27];
  const float* bd3    = (const float*)d_in[28];
  const float* Wd4    = (const float*)d_in[29];
  const float* bd4    = (const float*)d_in[30];
  float* out = (float*)d_out;

  // ---- workspace layout ----
  float* ws = (float*)d_ws;
  float* G  = ws;                                   // 4*512*2048 f32 = 16 MB
  float* h0 = G  + NREG*(size_t)BATCH*GW;           // fp32 state block (zeroed)
  float* c0 = h0 + (size_t)BATCH*HID;
  float* h1 = c0 + (size_t)BATCH*HID;
  float* c1 = h1 + (size_t)BATCH*HID;
  half_t* h0fh = (half_t*)(c1 + (size_t)BATCH*HID); // fp16 frag splits (zeroed)
  half_t* h0fl = h0fh + (size_t)BATCH*HID;
  half_t* h1fh = h0fl + (size_t)BATCH*HID;
  half_t* h1fl = h1fh + (size_t)BATCH*HID;
  float* mu = (float*)(h1fl + (size_t)BATCH*HID);   // 512
  float* rs = mu + BATCH;                           // 512
  half_t* Wh = (half_t*)(rs + BATCH);               // WTOT halves (packed)
  half_t* Wl = Wh + (size_t)WTOT;                   // WTOT halves (packed)
  half_t* xh = Wl + (size_t)WTOT;                   // XFRAG halves (frag-major)
  half_t* xl = xh + XFRAG;
  int* ctr = (int*)(xl + XFRAG);                    // 204 ints (per-tick flags)

  // zero h0,c0,h1,c1 (fp32) + 4 frag planes (fp16) in one contiguous memset
  (void)hipMemsetAsync(h0, 0, 4*(size_t)BATCH*HID*4 + 4*(size_t)BATCH*HID*2, stream);
  (void)hipMemsetAsync(ctr, 0, 204*sizeof(int), stream);

  ln1_stats<<<BATCH, 256, 0, stream>>>(x, mu, rs);
  wsplit<<<(WTOT+255)/256, 256, 0, stream>>>(W_ih0, W_hh0, W_ih1, W_hh1, Wh, Wl);
  xprep<<<(int)((XFRAG+255)/256), 256, 0, stream>>>(x, ln1_g, ln1_b, mu, rs, xh, xl);

  for (int t = 0; t <= SEQ; ++t) {
    tick_fused<<<dim3(NBLK_MM), 256, 0, stream>>>(xh, xl,
        h0fh, h0fl, h1fh, h1fl, Wh, Wl, G, ctr,
        b_ih0, b_hh0, b_ih1, b_hh1,
        g_ih0, be_ih0, g_hh0, be_hh0, g_ho0, be_ho0,
        g_ih1, be_ih1, g_hh1, be_hh1, g_ho1, be_ho1,
        c0, c1, h1, t);
  }
  head_kernel<<<BATCH, 256, 0, stream>>>(h1, Wd1, bd1, Wd2, bd2, Wd3, bd3, Wd4, bd4, out);
}

// Round 15
// 5706.665 us; speedup vs baseline: 3.5100x; 3.5100x over previous
//
#include <hip/hip_runtime.h>
#include <math.h>

#define BATCH 512
#define SEQ   200
#define DIN   64
#define HID   512
#define GW    2048   // 4*HID
#define EPS   1e-5f
#define NREG  4      // G regions: ih0 | hh0 | ih1 | hh1
#define MM_LDS 98304   // 3 x 32KB triple-buffered staging

typedef _Float16 half_t;
typedef half_t half8 __attribute__((ext_vector_type(8)));
typedef float  f32x4  __attribute__((ext_vector_type(4)));
typedef float  f32x16 __attribute__((ext_vector_type(16)));

#define WN0 (2048*64)     // W_ih0 elems
#define WN1 (2048*512)    // W_hh0 / W_ih1 / W_hh1 elems
#define WTOT (WN0 + 3*WN1)
#define XFRAG ((size_t)SEQ*16*4*512)   // per-plane xsplit elems (frag-major)

__device__ __forceinline__ float sigf(float x){ return 1.0f/(1.0f+expf(-x)); }

// async global->LDS, 16B per lane; LDS dest = wave-uniform base + lane*16 (HW)
__device__ __forceinline__ void gload16(const half_t* g, half_t* l){
  __builtin_amdgcn_global_load_lds(
      (const __attribute__((address_space(1))) void*)g,
      (__attribute__((address_space(3))) void*)l, 16, 0, 0);
}

__device__ __forceinline__ void barf(){
  asm volatile("" ::: "memory");
  __builtin_amdgcn_s_barrier();
  asm volatile("" ::: "memory");
}

// Reduce 4 values across a 256-thread block. red must be float[16] shared.
__device__ __forceinline__ void block_reduce4(float&a,float&b,float&c,float&d,float* red){
  #pragma unroll
  for(int o=32;o;o>>=1){
    a+=__shfl_down(a,o); b+=__shfl_down(b,o);
    c+=__shfl_down(c,o); d+=__shfl_down(d,o);
  }
  const int lane = threadIdx.x & 63, wid = threadIdx.x>>6;
  if(lane==0){ red[wid*4+0]=a; red[wid*4+1]=b; red[wid*4+2]=c; red[wid*4+3]=d; }
  __syncthreads();
  a = red[0]+red[4]+red[8]+red[12];
  b = red[1]+red[5]+red[9]+red[13];
  c = red[2]+red[6]+red[10]+red[14];
  d = red[3]+red[7]+red[11]+red[15];
  __syncthreads();
}

// Per-batch-row stats for ln1 (joint LayerNorm over (S,D) = 12800 elems)
__global__ __launch_bounds__(256) void ln1_stats(const float* __restrict__ x,
                                                 float* __restrict__ mu,
                                                 float* __restrict__ rs){
  const int b = blockIdx.x;
  const float* xb = x + (size_t)b*SEQ*DIN;
  float s=0, ss=0, d=0, e=0;
  for (int i=threadIdx.x; i<SEQ*DIN; i+=256){ float v=xb[i]; s+=v; ss+=v*v; }
  __shared__ float red[16];
  block_reduce4(s,ss,d,e,red);
  if (threadIdx.x==0){
    float m = s*(1.0f/(SEQ*DIN));
    mu[b] = m;
    rs[b] = rsqrtf(ss*(1.0f/(SEQ*DIN)) - m*m + EPS);
  }
}

// Split the 4 weight matrices into fp16 hi/lo in FRAGMENT-MAJOR packed layout.
//   idx = ((p*C + c)*4 + nf*2 + ks)*512 + l*8 + j
//   n = p*64 + nf*32 + (l&31);  k = c*32 + ks*16 + (l>>5)*8 + j
__global__ __launch_bounds__(256) void wsplit(
    const float* __restrict__ W0, const float* __restrict__ W1,
    const float* __restrict__ W2, const float* __restrict__ W3,
    half_t* __restrict__ Wh, half_t* __restrict__ Wl)
{
  int i = blockIdx.x*256 + threadIdx.x;
  if (i >= WTOT) return;
  const float* src; int off, Kd;
  if (i < WN0){ src=W0; off=i; Kd=DIN; }
  else {
    int r = (i-WN0)/WN1; off = (i-WN0) - r*WN1; Kd=HID;
    src = (r==0)?W1:((r==1)?W2:W3);
  }
  const int C = Kd>>5;            // 2 or 16 (pow2)
  int j  = off & 7;
  int l  = (off>>3) & 63;
  int ks = (off>>9) & 1;
  int nf = (off>>10) & 1;
  int pc = off>>11;
  int c  = pc & (C-1);
  int p  = pc >> (Kd==DIN ? 1 : 4);
  int n  = p*64 + nf*32 + (l&31);
  int k  = c*32 + ks*16 + (l>>5)*8 + j;
  float v = src[(size_t)n*Kd + k];
  half_t h = (half_t)v;
  Wh[i] = h;
  Wl[i] = (half_t)(v - (float)h);
}

// Precompute ln1(x) fp16 hi/lo splits for ALL t in MFMA-A-fragment layout:
//   idx = ((t*16 + mch)*4 + c)*512 + l*8 + j
//   b = mch*32 + (l&31);  k = c*16 + (l>>5)*8 + j
__global__ __launch_bounds__(256) void xprep(
    const float* __restrict__ x, const float* __restrict__ g1, const float* __restrict__ b1,
    const float* __restrict__ mu, const float* __restrict__ rs,
    half_t* __restrict__ xh, half_t* __restrict__ xl)
{
  size_t i = (size_t)blockIdx.x*256 + threadIdx.x;
  if (i >= XFRAG) return;
  int j   = (int)(i & 7);
  int l   = (int)((i>>3) & 63);
  int c   = (int)((i>>9) & 3);
  int mch = (int)((i>>11) & 15);
  int t   = (int)(i>>15);
  int b   = mch*32 + (l&31);
  int k   = c*16 + ((l>>5)<<3) + j;
  float v = (x[(size_t)b*(SEQ*DIN) + t*DIN + k] - mu[b]) * rs[b]
            * g1[t*DIN+k] + b1[t*DIN+k];
  half_t h = (half_t)v;
  xh[i] = h;
  xl[i] = (half_t)(v - (float)h);
}

// One tick: gate pre-activation GEMMs via split-fp16 32x32x16 MFMA.
// LDS-staged, TRIPLE-buffered (3 x 32KB dynamic LDS), depth-2 prefetch:
//   prologue stage(0), stage(1);
//   step s: { vmcnt(8) [retire stage s; keep s+1 in flight]; barrier;
//             stage(s+2); compute(s) x2 }
// The retiring stage had ~2 compute phases in flight -> LLC latency covered.
// Single barrier/step is safe: stage(s+3) (rewrites buf[s%3]) is issued only
// after barrier(s+1), which post-dates every wave's compute(s).
// Block = 128m x 128n (2x2 waves, wave tile 64x64); grid 256 = 1 block/CU.
__global__ __launch_bounds__(256, 1) void tick_mm64(
    const half_t* __restrict__ xh, const half_t* __restrict__ xl,
    const half_t* __restrict__ h0fh, const half_t* __restrict__ h0fl,
    const half_t* __restrict__ h1fh, const half_t* __restrict__ h1fl,
    const half_t* __restrict__ Wh, const half_t* __restrict__ Wl,
    float* __restrict__ G, int t)
{
  extern __shared__ half_t sbuf[];       // 3 x 16384 halves (3 x 32KB)

  const int bi   = blockIdx.x;
  const int xcd  = bi & 7;
  const int slot = bi >> 3;
  const int z    = slot & 3;             // region 0..3
  const int y    = (slot >> 2) & 3;      // m-group 0..3
  const int x    = xcd*2 + (slot >> 4);  // n-group 0..15

  const int tid  = threadIdx.x;
  const int lane = tid & 63;
  const int w    = tid >> 6;
  const int ln31 = lane & 31;

  const int mch0 = y*4 + (w>>1)*2;       // wave's two 32-row m-chunks
  const int p    = x*2 + (w&1);          // wave's 64-col panel (global)
  const int wn0  = p*64;

  const half_t* BHb = Wh + WN0; const half_t* BLb = Wl + WN0;
  int Kd = HID;
  if (z==0){ BHb=Wh; BLb=Wl; Kd=DIN; }
  else if (z==2){ BHb=Wh+WN0+WN1; BLb=Wl+WN0+WN1; }
  else if (z==3){ BHb=Wh+WN0+2*WN1; BLb=Wl+WN0+2*WN1; }

  const int C32 = Kd >> 5;               // K-steps: 2 or 16
  const int C16 = Kd >> 4;

  const int tq = (t < SEQ) ? t : (SEQ-1);   // t==200 region0 result unused
  const half_t *AHb, *ALb;
  if (z==0){ AHb = xh + (size_t)tq*32768; ALb = xl + (size_t)tq*32768; }
  else if (z==3){ AHb = h1fh; ALb = h1fl; }
  else { AHb = h0fh; ALb = h0fl; }

  // staging: waves 0,1 -> A (mch pairs); waves 2,3 -> B (one panel each); 8 loads/wave
  auto stage = [&](int s){
    half_t* dst = sbuf + (size_t)(s%3)*16384;
    if (w < 2){
      #pragma unroll
      for (int q=0;q<2;q++){
        const int mci = w*2+q;
        const size_t abase = ((size_t)(y*4+mci)*C16 + 2*s)*512;
        #pragma unroll
        for (int pl=0;pl<2;pl++){
          const half_t* src = (pl? ALb : AHb) + abase + lane*8;
          half_t* d = dst + (mci*2+pl)*1024;
          gload16(src,       d);
          gload16(src + 512, d + 512);
        }
      }
    } else {
      const int ph = w-2;
      const size_t bbase = ((size_t)(x*2+ph)*C32 + s)*2048;
      #pragma unroll
      for (int pl=0;pl<2;pl++){
        const half_t* src = (pl? BLb : BHb) + bbase + lane*8;
        half_t* d = dst + 8192 + (ph*2+pl)*2048;
        #pragma unroll
        for (int i=0;i<4;i++)
          gload16(src + i*512, d + i*512);
      }
    }
  };

  f32x16 acc00 = {0.f,0.f,0.f,0.f,0.f,0.f,0.f,0.f,0.f,0.f,0.f,0.f,0.f,0.f,0.f,0.f};
  f32x16 acc01 = acc00, acc10 = acc00, acc11 = acc00;

  const int mh = w>>1, pw = w&1;
  auto compute = [&](const half_t* buf, int ks){
    const half_t* Ab = buf;
    const half_t* Bb = buf + 8192;
    half8 ah0 = *(const half8*)(Ab + ((mh*2+0)*2+0)*1024 + ks*512 + lane*8);
    half8 al0 = *(const half8*)(Ab + ((mh*2+0)*2+1)*1024 + ks*512 + lane*8);
    half8 ah1 = *(const half8*)(Ab + ((mh*2+1)*2+0)*1024 + ks*512 + lane*8);
    half8 al1 = *(const half8*)(Ab + ((mh*2+1)*2+1)*1024 + ks*512 + lane*8);
    half8 bh0 = *(const half8*)(Bb + ((pw*2+0)*4 + 0 + ks)*512 + lane*8);
    half8 bh1 = *(const half8*)(Bb + ((pw*2+0)*4 + 2 + ks)*512 + lane*8);
    half8 bl0 = *(const half8*)(Bb + ((pw*2+1)*4 + 0 + ks)*512 + lane*8);
    half8 bl1 = *(const half8*)(Bb + ((pw*2+1)*4 + 2 + ks)*512 + lane*8);
    acc00 = __builtin_amdgcn_mfma_f32_32x32x16_f16(ah0, bh0, acc00, 0,0,0);
    acc01 = __builtin_amdgcn_mfma_f32_32x32x16_f16(ah0, bh1, acc01, 0,0,0);
    acc10 = __builtin_amdgcn_mfma_f32_32x32x16_f16(ah1, bh0, acc10, 0,0,0);
    acc11 = __builtin_amdgcn_mfma_f32_32x32x16_f16(ah1, bh1, acc11, 0,0,0);
    acc00 = __builtin_amdgcn_mfma_f32_32x32x16_f16(al0, bh0, acc00, 0,0,0);
    acc01 = __builtin_amdgcn_mfma_f32_32x32x16_f16(al0, bh1, acc01, 0,0,0);
    acc10 = __builtin_amdgcn_mfma_f32_32x32x16_f16(al1, bh0, acc10, 0,0,0);
    acc11 = __builtin_amdgcn_mfma_f32_32x32x16_f16(al1, bh1, acc11, 0,0,0);
    acc00 = __builtin_amdgcn_mfma_f32_32x32x16_f16(ah0, bl0, acc00, 0,0,0);
    acc01 = __builtin_amdgcn_mfma_f32_32x32x16_f16(ah0, bl1, acc01, 0,0,0);
    acc10 = __builtin_amdgcn_mfma_f32_32x32x16_f16(ah1, bl0, acc10, 0,0,0);
    acc11 = __builtin_amdgcn_mfma_f32_32x32x16_f16(ah1, bl1, acc11, 0,0,0);
  };

  stage(0);
  if (C32 > 1) stage(1);
  for (int s=0; s<C32; ++s){
    if (s+1 < C32)
      asm volatile("s_waitcnt vmcnt(8)" ::: "memory");  // retire stage s, keep s+1 in flight
    else
      asm volatile("s_waitcnt vmcnt(0)" ::: "memory");
    __builtin_amdgcn_sched_barrier(0);
    barf();                                             // single barrier per step
    if (s+2 < C32) stage(s+2);                          // depth-2 prefetch
    const half_t* buf = sbuf + (size_t)(s%3)*16384;
    compute(buf, 0);
    compute(buf, 1);
  }

  // C/D 32x32: col = lane&31, row = (reg&3)+8*(reg>>2)+4*(lane>>5)
  // Nontemporal: G streams to L3/HBM.
  float* Gr = G + (size_t)z*BATCH*GW;
  const int rbase = (lane>>5)<<2;
  #pragma unroll
  for (int reg=0; reg<16; reg++){
    const int row = (reg&3) + ((reg>>2)<<3) + rbase;
    const int m0 = mch0*32 + row;
    const int m1 = m0 + 32;
    __builtin_nontemporal_store(acc00[reg], &Gr[(size_t)m0*GW + wn0 + ln31]);
    __builtin_nontemporal_store(acc01[reg], &Gr[(size_t)m0*GW + wn0 + 32 + ln31]);
    __builtin_nontemporal_store(acc10[reg], &Gr[(size_t)m1*GW + wn0 + ln31]);
    __builtin_nontemporal_store(acc11[reg], &Gr[(size_t)m1*GW + wn0 + 32 + ln31]);
  }
}

// One block per (layer, batch-row): bias + gate LN + cell update + h LN.
// Emits h fp16 hi/lo splits in MFMA-fragment-major layout (h1 fp32 only at t=SEQ).
__global__ __launch_bounds__(256) void tick_update(
    const float* __restrict__ G,
    const float* __restrict__ b_ih0, const float* __restrict__ b_hh0,
    const float* __restrict__ b_ih1, const float* __restrict__ b_hh1,
    const float* __restrict__ g_ih0, const float* __restrict__ be_ih0,
    const float* __restrict__ g_hh0, const float* __restrict__ be_hh0,
    const float* __restrict__ g_ho0, const float* __restrict__ be_ho0,
    const float* __restrict__ g_ih1, const float* __restrict__ be_ih1,
    const float* __restrict__ g_hh1, const float* __restrict__ be_hh1,
    const float* __restrict__ g_ho1, const float* __restrict__ be_ho1,
    float* __restrict__ h0, float* __restrict__ c0,
    float* __restrict__ h1, float* __restrict__ c1,
    half_t* __restrict__ h0fh, half_t* __restrict__ h0fl,
    half_t* __restrict__ h1fh, half_t* __restrict__ h1fl, int t)
{
  const int layer = blockIdx.x >> 9;
  const int b = blockIdx.x & 511;
  if (layer==0 && t>=SEQ) return;   // layer0 active ticks 0..199
  if (layer==1 && t==0)   return;   // layer1 active ticks 1..200 (processes step t-1)

  const float *GA,*GB,*bA,*bB,*gA,*beA,*gB,*beB,*gH,*bH;
  float *cs,*hs; half_t *hfx,*lfx;
  const size_t rb = (size_t)b*GW;
  if (layer==0){
    GA = G + rb;
    GB = G + (size_t)1*BATCH*GW + rb;
    bA=b_ih0; bB=b_hh0;
    gA=g_ih0; beA=be_ih0; gB=g_hh0; beB=be_hh0; gH=g_ho0; bH=be_ho0;
    cs = c0 + b*HID; hs = nullptr; hfx = h0fh; lfx = h0fl;
  } else {
    GA = G + (size_t)2*BATCH*GW + rb;
    GB = G + (size_t)3*BATCH*GW + rb;
    bA=b_ih1; bB=b_hh1;
    gA=g_ih1; beA=be_ih1; gB=g_hh1; beB=be_hh1; gH=g_ho1; bH=be_ho1;
    cs = c1 + b*HID; hs = (t==SEQ) ? (h1 + b*HID) : nullptr; hfx = h1fh; lfx = h1fl;
  }

  const int tid = threadIdx.x;
  __shared__ float red[16];
  __shared__ __align__(16) float GS[2*GW];     // 16 KB: A-part then B-part
  __shared__ float su[HID];
  __shared__ float so[HID];

  // Pass 1 (f32x4, nontemporal): bias add, stage into LDS, LN stats
  float sa=0, ssa=0, sb=0, ssb=0;
  for (int i=tid*4; i<GW; i+=1024){
    f32x4 va = __builtin_nontemporal_load((const f32x4*)(GA+i));
    va += *(const f32x4*)(bA+i);
    *(f32x4*)(GS+i) = va;
    f32x4 vb = __builtin_nontemporal_load((const f32x4*)(GB+i));
    vb += *(const f32x4*)(bB+i);
    *(f32x4*)(GS+GW+i) = vb;
    #pragma unroll
    for (int q=0;q<4;q++){
      sa += va[q]; ssa += va[q]*va[q];
      sb += vb[q]; ssb += vb[q]*vb[q];
    }
  }
  block_reduce4(sa,ssa,sb,ssb,red);   // internal __syncthreads covers GS visibility
  const float ma = sa*(1.0f/GW);
  const float ra = rsqrtf(ssa*(1.0f/GW) - ma*ma + EPS);
  const float mb = sb*(1.0f/GW);
  const float rb_ = rsqrtf(ssb*(1.0f/GW) - mb*mb + EPS);

  // Pass 2: gates (i,f,g,o split), cell update, tanh(c) stats
  float s_u=0, s_uu=0;
  for (int j=tid;j<HID;j+=256){
    float iv = ((GS[j      ]-ma)*ra*gA[j      ]+beA[j      ]) + ((GS[GW+j      ]-mb)*rb_*gB[j      ]+beB[j      ]);
    float fv = ((GS[j+  HID]-ma)*ra*gA[j+  HID]+beA[j+  HID]) + ((GS[GW+j+  HID]-mb)*rb_*gB[j+  HID]+beB[j+  HID]);
    float gv = ((GS[j+2*HID]-ma)*ra*gA[j+2*HID]+beA[j+2*HID]) + ((GS[GW+j+2*HID]-mb)*rb_*gB[j+2*HID]+beB[j+2*HID]);
    float ov = ((GS[j+3*HID]-ma)*ra*gA[j+3*HID]+beA[j+3*HID]) + ((GS[GW+j+3*HID]-mb)*rb_*gB[j+3*HID]+beB[j+3*HID]);
    float cn = sigf(fv)*cs[j] + sigf(iv)*tanhf(gv);
    cs[j] = cn;
    float u = tanhf(cn);
    su[j] = u; so[j] = sigf(ov);
    s_u += u; s_uu += u*u;
  }
  float d3=0,d4=0;
  block_reduce4(s_u,s_uu,d3,d4,red);
  const float mu_u = s_u*(1.0f/HID);
  const float ru   = rsqrtf(s_uu*(1.0f/HID) - mu_u*mu_u + EPS);

  // Pass 3: h = sigmoid(o) * LN(tanh(c)); fp16 hi/lo in fragment layout
  const size_t fbase = ((size_t)(b>>5)*32)*512 + (size_t)(b&31)*8;
  for (int j=tid;j<HID;j+=256){
    float v = so[j] * ((su[j]-mu_u)*ru*gH[j] + bH[j]);
    if (hs) hs[j] = v;
    half_t hv = (half_t)v;
    half_t lv = (half_t)(v - (float)hv);
    const size_t fi = fbase + (size_t)(j>>4)*512 + (size_t)((j>>3)&1)*256 + (j&7);
    hfx[fi] = hv;
    lfx[fi] = lv;
  }
}

// Dense head: 512 -> 128 -> 64 -> 32 -> 1, one block per batch row
__global__ __launch_bounds__(256) void head_kernel(
    const float* __restrict__ h1,
    const float* __restrict__ Wd1, const float* __restrict__ bd1,
    const float* __restrict__ Wd2, const float* __restrict__ bd2,
    const float* __restrict__ Wd3, const float* __restrict__ bd3,
    const float* __restrict__ Wd4, const float* __restrict__ bd4,
    float* __restrict__ out)
{
  const int b = blockIdx.x;
  __shared__ float hv[HID];
  __shared__ float z1[128];
  __shared__ float z2[64];
  __shared__ float z3[32];
  const int tid = threadIdx.x;
  for (int i=tid;i<HID;i+=256) hv[i]=h1[(size_t)b*HID+i];
  __syncthreads();
  if (tid<128){
    float acc=bd1[tid]; const float* w=Wd1+(size_t)tid*512;
    for(int k=0;k<512;k++) acc+=hv[k]*w[k];
    z1[tid]=fmaxf(acc,0.f);
  }
  __syncthreads();
  if (tid<64){
    float acc=bd2[tid]; const float* w=Wd2+(size_t)tid*128;
    for(int k=0;k<128;k++) acc+=z1[k]*w[k];
    z2[tid]=fmaxf(acc,0.f);
  }
  __syncthreads();
  if (tid<32){
    float acc=bd3[tid]; const float* w=Wd3+(size_t)tid*64;
    for(int k=0;k<64;k++) acc+=z2[k]*w[k];
    z3[tid]=fmaxf(acc,0.f);
  }
  __syncthreads();
  if (tid==0){
    float acc=bd4[0];
    for(int k=0;k<32;k++) acc+=z3[k]*Wd4[k];
    out[b]=acc;
  }
}

extern "C" void kernel_launch(void* const* d_in, const int* in_sizes, int n_in,
                              void* d_out, int out_size, void* d_ws, size_t ws_size,
                              hipStream_t stream) {
  const float* x      = (const float*)d_in[0];
  const float* ln1_g  = (const float*)d_in[1];
  const float* ln1_b  = (const float*)d_in[2];
  const float* W_ih0  = (const float*)d_in[3];
  const float* b_ih0  = (const float*)d_in[4];
  const float* W_hh0  = (const float*)d_in[5];
  const float* b_hh0  = (const float*)d_in[6];
  const float* g_ih0  = (const float*)d_in[7];
  const float* be_ih0 = (const float*)d_in[8];
  const float* g_hh0  = (const float*)d_in[9];
  const float* be_hh0 = (const float*)d_in[10];
  const float* g_ho0  = (const float*)d_in[11];
  const float* be_ho0 = (const float*)d_in[12];
  const float* W_ih1  = (const float*)d_in[13];
  const float* b_ih1  = (const float*)d_in[14];
  const float* W_hh1  = (const float*)d_in[15];
  const float* b_hh1  = (const float*)d_in[16];
  const float* g_ih1  = (const float*)d_in[17];
  const float* be_ih1 = (const float*)d_in[18];
  const float* g_hh1  = (const float*)d_in[19];
  const float* be_hh1 = (const float*)d_in[20];
  const float* g_ho1  = (const float*)d_in[21];
  const float* be_ho1 = (const float*)d_in[22];
  const float* Wd1    = (const float*)d_in[23];
  const float* bd1    = (const float*)d_in[24];
  const float* Wd2    = (const float*)d_in[25];
  const float* bd2    = (const float*)d_in[26];
  const float* Wd3    = (const float*)d_in[27];
  const float* bd3    = (const float*)d_in[28];
  const float* Wd4    = (const float*)d_in[29];
  const float* bd4    = (const float*)d_in[30];
  float* out = (float*)d_out;

  // ---- workspace layout ----
  float* ws = (float*)d_ws;
  float* G  = ws;                                   // 4*512*2048 f32 = 16 MB
  float* h0 = G  + NREG*(size_t)BATCH*GW;           // fp32 state block (zeroed)
  float* c0 = h0 + (size_t)BATCH*HID;
  float* h1 = c0 + (size_t)BATCH*HID;
  float* c1 = h1 + (size_t)BATCH*HID;
  half_t* h0fh = (half_t*)(c1 + (size_t)BATCH*HID); // fp16 frag splits (zeroed)
  half_t* h0fl = h0fh + (size_t)BATCH*HID;
  half_t* h1fh = h0fl + (size_t)BATCH*HID;
  half_t* h1fl = h1fh + (size_t)BATCH*HID;
  float* mu = (float*)(h1fl + (size_t)BATCH*HID);   // 512
  float* rs = mu + BATCH;                           // 512
  half_t* Wh = (half_t*)(rs + BATCH);               // WTOT halves (packed)
  half_t* Wl = Wh + (size_t)WTOT;                   // WTOT halves (packed)
  half_t* xh = Wl + (size_t)WTOT;                   // XFRAG halves (frag-major)
  half_t* xl = xh + XFRAG;

  // zero h0,c0,h1,c1 (fp32) + 4 frag planes (fp16) in one contiguous memset
  (void)hipMemsetAsync(h0, 0, 4*(size_t)BATCH*HID*4 + 4*(size_t)BATCH*HID*2, stream);

  static int attr_done = 0;
  if (!attr_done){
    (void)hipFuncSetAttribute((const void*)tick_mm64,
        hipFuncAttributeMaxDynamicSharedMemorySize, MM_LDS);
    attr_done = 1;
  }

  ln1_stats<<<BATCH, 256, 0, stream>>>(x, mu, rs);
  wsplit<<<(WTOT+255)/256, 256, 0, stream>>>(W_ih0, W_hh0, W_ih1, W_hh1, Wh, Wl);
  xprep<<<(int)((XFRAG+255)/256), 256, 0, stream>>>(x, ln1_g, ln1_b, mu, rs, xh, xl);

  for (int t = 0; t <= SEQ; ++t) {
    tick_mm64<<<dim3(256), 256, MM_LDS, stream>>>(xh, xl,
        h0fh, h0fl, h1fh, h1fl, Wh, Wl, G, t);
    tick_update<<<dim3(1024), 256, 0, stream>>>(G,
        b_ih0, b_hh0, b_ih1, b_hh1,
        g_ih0, be_ih0, g_hh0, be_hh0, g_ho0, be_ho0,
        g_ih1, be_ih1, g_hh1, be_hh1, g_ho1, be_ho1,
        h0, c0, h1, c1, h0fh, h0fl, h1fh, h1fl, t);
  }
  head_kernel<<<BATCH, 256, 0, stream>>>(h1, Wd1, bd1, Wd2, bd2, Wd3, bd3, Wd4, bd4, out);
}

// Round 16
// 5458.349 us; speedup vs baseline: 3.6697x; 1.0455x over previous
//
#include <hip/hip_runtime.h>
#include <math.h>

#define BATCH 512
#define SEQ   200
#define DIN   64
#define HID   512
#define GW    2048   // 4*HID
#define EPS   1e-5f
#define NREG  4      // G regions: ih0 | hh0 | ih1 | hh1

typedef _Float16 half_t;
typedef half_t half8 __attribute__((ext_vector_type(8)));
typedef float  f32x4  __attribute__((ext_vector_type(4)));
typedef float  f32x16 __attribute__((ext_vector_type(16)));

#define WN0 (2048*64)     // W_ih0 elems
#define WN1 (2048*512)    // W_hh0 / W_ih1 / W_hh1 elems
#define WTOT (WN0 + 3*WN1)
#define XFRAG ((size_t)SEQ*16*4*512)   // per-plane xsplit elems (frag-major)

__device__ __forceinline__ float sigf(float x){ return 1.0f/(1.0f+expf(-x)); }

// async global->LDS, 16B per lane; LDS dest = wave-uniform base + lane*16 (HW)
__device__ __forceinline__ void gload16(const half_t* g, half_t* l){
  __builtin_amdgcn_global_load_lds(
      (const __attribute__((address_space(1))) void*)g,
      (__attribute__((address_space(3))) void*)l, 16, 0, 0);
}

__device__ __forceinline__ void barf(){
  asm volatile("" ::: "memory");
  __builtin_amdgcn_s_barrier();
  asm volatile("" ::: "memory");
}

// Reduce 4 values across a 256-thread block. red must be float[16] shared.
__device__ __forceinline__ void block_reduce4(float&a,float&b,float&c,float&d,float* red){
  #pragma unroll
  for(int o=32;o;o>>=1){
    a+=__shfl_down(a,o); b+=__shfl_down(b,o);
    c+=__shfl_down(c,o); d+=__shfl_down(d,o);
  }
  const int lane = threadIdx.x & 63, wid = threadIdx.x>>6;
  if(lane==0){ red[wid*4+0]=a; red[wid*4+1]=b; red[wid*4+2]=c; red[wid*4+3]=d; }
  __syncthreads();
  a = red[0]+red[4]+red[8]+red[12];
  b = red[1]+red[5]+red[9]+red[13];
  c = red[2]+red[6]+red[10]+red[14];
  d = red[3]+red[7]+red[11]+red[15];
  __syncthreads();
}

// Per-batch-row stats for ln1 (joint LayerNorm over (S,D) = 12800 elems)
__global__ __launch_bounds__(256) void ln1_stats(const float* __restrict__ x,
                                                 float* __restrict__ mu,
                                                 float* __restrict__ rs){
  const int b = blockIdx.x;
  const float* xb = x + (size_t)b*SEQ*DIN;
  float s=0, ss=0, d=0, e=0;
  for (int i=threadIdx.x; i<SEQ*DIN; i+=256){ float v=xb[i]; s+=v; ss+=v*v; }
  __shared__ float red[16];
  block_reduce4(s,ss,d,e,red);
  if (threadIdx.x==0){
    float m = s*(1.0f/(SEQ*DIN));
    mu[b] = m;
    rs[b] = rsqrtf(ss*(1.0f/(SEQ*DIN)) - m*m + EPS);
  }
}

// Split the 4 weight matrices into fp16 hi/lo in FRAGMENT-MAJOR packed layout.
//   idx = ((p*C + c)*4 + nf*2 + ks)*512 + l*8 + j
//   n = p*64 + nf*32 + (l&31);  k = c*32 + ks*16 + (l>>5)*8 + j
__global__ __launch_bounds__(256) void wsplit(
    const float* __restrict__ W0, const float* __restrict__ W1,
    const float* __restrict__ W2, const float* __restrict__ W3,
    half_t* __restrict__ Wh, half_t* __restrict__ Wl)
{
  int i = blockIdx.x*256 + threadIdx.x;
  if (i >= WTOT) return;
  const float* src; int off, Kd;
  if (i < WN0){ src=W0; off=i; Kd=DIN; }
  else {
    int r = (i-WN0)/WN1; off = (i-WN0) - r*WN1; Kd=HID;
    src = (r==0)?W1:((r==1)?W2:W3);
  }
  const int C = Kd>>5;            // 2 or 16 (pow2)
  int j  = off & 7;
  int l  = (off>>3) & 63;
  int ks = (off>>9) & 1;
  int nf = (off>>10) & 1;
  int pc = off>>11;
  int c  = pc & (C-1);
  int p  = pc >> (Kd==DIN ? 1 : 4);
  int n  = p*64 + nf*32 + (l&31);
  int k  = c*32 + ks*16 + (l>>5)*8 + j;
  float v = src[(size_t)n*Kd + k];
  half_t h = (half_t)v;
  Wh[i] = h;
  Wl[i] = (half_t)(v - (float)h);
}

// Precompute ln1(x) fp16 hi/lo splits for ALL t in MFMA-A-fragment layout:
//   idx = ((t*16 + mch)*4 + c)*512 + l*8 + j
//   b = mch*32 + (l&31);  k = c*16 + (l>>5)*8 + j
__global__ __launch_bounds__(256) void xprep(
    const float* __restrict__ x, const float* __restrict__ g1, const float* __restrict__ b1,
    const float* __restrict__ mu, const float* __restrict__ rs,
    half_t* __restrict__ xh, half_t* __restrict__ xl)
{
  size_t i = (size_t)blockIdx.x*256 + threadIdx.x;
  if (i >= XFRAG) return;
  int j   = (int)(i & 7);
  int l   = (int)((i>>3) & 63);
  int c   = (int)((i>>9) & 3);
  int mch = (int)((i>>11) & 15);
  int t   = (int)(i>>15);
  int b   = mch*32 + (l&31);
  int k   = c*16 + ((l>>5)<<3) + j;
  float v = (x[(size_t)b*(SEQ*DIN) + t*DIN + k] - mu[b]) * rs[b]
            * g1[t*DIN+k] + b1[t*DIN+k];
  half_t h = (half_t)v;
  xh[i] = h;
  xl[i] = (half_t)(v - (float)h);
}

// One tick: gate pre-activation GEMMs via split-fp16 32x32x16 MFMA.
// R10 structure (best measured): LDS-staged operands, double-buffered,
// counted vmcnt(8); block = 128m x 128n (2x2 waves, wave 64x64);
// grid 256 = 1 block/CU; XCD-pinned decode.
// CHANGE vs R10: G stores are PLAIN (not nontemporal) — G (16 MB) stays in
// L2/LLC instead of being forced to HBM; upd reads then hit cache.
__global__ __launch_bounds__(256, 1) void tick_mm64(
    const half_t* __restrict__ xh, const half_t* __restrict__ xl,
    const half_t* __restrict__ h0fh, const half_t* __restrict__ h0fl,
    const half_t* __restrict__ h1fh, const half_t* __restrict__ h1fl,
    const half_t* __restrict__ Wh, const half_t* __restrict__ Wl,
    float* __restrict__ G, int t)
{
  __shared__ half_t sbuf[2*16384];       // 2 x 32KB (halves)

  const int bi   = blockIdx.x;
  const int xcd  = bi & 7;
  const int slot = bi >> 3;
  const int z    = slot & 3;             // region 0..3
  const int y    = (slot >> 2) & 3;      // m-group 0..3
  const int x    = xcd*2 + (slot >> 4);  // n-group 0..15

  const int tid  = threadIdx.x;
  const int lane = tid & 63;
  const int w    = tid >> 6;
  const int ln31 = lane & 31;

  const int mch0 = y*4 + (w>>1)*2;       // wave's two 32-row m-chunks
  const int p    = x*2 + (w&1);          // wave's 64-col panel (global)
  const int wn0  = p*64;

  const half_t* BHb = Wh + WN0; const half_t* BLb = Wl + WN0;
  int Kd = HID;
  if (z==0){ BHb=Wh; BLb=Wl; Kd=DIN; }
  else if (z==2){ BHb=Wh+WN0+WN1; BLb=Wl+WN0+WN1; }
  else if (z==3){ BHb=Wh+WN0+2*WN1; BLb=Wl+WN0+2*WN1; }

  const int C32 = Kd >> 5;               // K-steps: 2 or 16
  const int C16 = Kd >> 4;

  const int tq = (t < SEQ) ? t : (SEQ-1);   // t==200 region0 result unused
  const half_t *AHb, *ALb;
  if (z==0){ AHb = xh + (size_t)tq*32768; ALb = xl + (size_t)tq*32768; }
  else if (z==3){ AHb = h1fh; ALb = h1fl; }
  else { AHb = h0fh; ALb = h0fl; }

  // staging: waves 0,1 -> A (mch pairs); waves 2,3 -> B (one panel each)
  auto stage = [&](int s){
    half_t* dst = sbuf + (size_t)(s&1)*16384;
    if (w < 2){
      #pragma unroll
      for (int q=0;q<2;q++){
        const int mci = w*2+q;
        const size_t abase = ((size_t)(y*4+mci)*C16 + 2*s)*512;
        #pragma unroll
        for (int pl=0;pl<2;pl++){
          const half_t* src = (pl? ALb : AHb) + abase + lane*8;
          half_t* d = dst + (mci*2+pl)*1024;
          gload16(src,       d);
          gload16(src + 512, d + 512);
        }
      }
    } else {
      const int ph = w-2;
      const size_t bbase = ((size_t)(x*2+ph)*C32 + s)*2048;
      #pragma unroll
      for (int pl=0;pl<2;pl++){
        const half_t* src = (pl? BLb : BHb) + bbase + lane*8;
        half_t* d = dst + 8192 + (ph*2+pl)*2048;
        #pragma unroll
        for (int i=0;i<4;i++)
          gload16(src + i*512, d + i*512);
      }
    }
  };

  f32x16 acc00 = {0.f,0.f,0.f,0.f,0.f,0.f,0.f,0.f,0.f,0.f,0.f,0.f,0.f,0.f,0.f,0.f};
  f32x16 acc01 = acc00, acc10 = acc00, acc11 = acc00;

  const int mh = w>>1, pw = w&1;
  auto compute = [&](const half_t* buf, int ks){
    const half_t* Ab = buf;
    const half_t* Bb = buf + 8192;
    half8 ah0 = *(const half8*)(Ab + ((mh*2+0)*2+0)*1024 + ks*512 + lane*8);
    half8 al0 = *(const half8*)(Ab + ((mh*2+0)*2+1)*1024 + ks*512 + lane*8);
    half8 ah1 = *(const half8*)(Ab + ((mh*2+1)*2+0)*1024 + ks*512 + lane*8);
    half8 al1 = *(const half8*)(Ab + ((mh*2+1)*2+1)*1024 + ks*512 + lane*8);
    half8 bh0 = *(const half8*)(Bb + ((pw*2+0)*4 + 0 + ks)*512 + lane*8);
    half8 bh1 = *(const half8*)(Bb + ((pw*2+0)*4 + 2 + ks)*512 + lane*8);
    half8 bl0 = *(const half8*)(Bb + ((pw*2+1)*4 + 0 + ks)*512 + lane*8);
    half8 bl1 = *(const half8*)(Bb + ((pw*2+1)*4 + 2 + ks)*512 + lane*8);
    acc00 = __builtin_amdgcn_mfma_f32_32x32x16_f16(ah0, bh0, acc00, 0,0,0);
    acc01 = __builtin_amdgcn_mfma_f32_32x32x16_f16(ah0, bh1, acc01, 0,0,0);
    acc10 = __builtin_amdgcn_mfma_f32_32x32x16_f16(ah1, bh0, acc10, 0,0,0);
    acc11 = __builtin_amdgcn_mfma_f32_32x32x16_f16(ah1, bh1, acc11, 0,0,0);
    acc00 = __builtin_amdgcn_mfma_f32_32x32x16_f16(al0, bh0, acc00, 0,0,0);
    acc01 = __builtin_amdgcn_mfma_f32_32x32x16_f16(al0, bh1, acc01, 0,0,0);
    acc10 = __builtin_amdgcn_mfma_f32_32x32x16_f16(al1, bh0, acc10, 0,0,0);
    acc11 = __builtin_amdgcn_mfma_f32_32x32x16_f16(al1, bh1, acc11, 0,0,0);
    acc00 = __builtin_amdgcn_mfma_f32_32x32x16_f16(ah0, bl0, acc00, 0,0,0);
    acc01 = __builtin_amdgcn_mfma_f32_32x32x16_f16(ah0, bl1, acc01, 0,0,0);
    acc10 = __builtin_amdgcn_mfma_f32_32x32x16_f16(ah1, bl0, acc10, 0,0,0);
    acc11 = __builtin_amdgcn_mfma_f32_32x32x16_f16(ah1, bl1, acc11, 0,0,0);
  };

  stage(0);
  for (int s=0; s<C32; ++s){
    if (s+1 < C32){
      stage(s+1);
      asm volatile("s_waitcnt vmcnt(8)" ::: "memory");   // retire step-s loads, keep s+1 in flight
    } else {
      asm volatile("s_waitcnt vmcnt(0)" ::: "memory");
    }
    __builtin_amdgcn_sched_barrier(0);
    barf();
    const half_t* buf = sbuf + (size_t)(s&1)*16384;
    compute(buf, 0);
    compute(buf, 1);
    barf();
  }

  // C/D 32x32: col = lane&31, row = (reg&3)+8*(reg>>2)+4*(lane>>5)
  // PLAIN stores: G stays cache-resident (L2 -> LLC at kernel end), not HBM.
  float* Gr = G + (size_t)z*BATCH*GW;
  const int rbase = (lane>>5)<<2;
  #pragma unroll
  for (int reg=0; reg<16; reg++){
    const int row = (reg&3) + ((reg>>2)<<3) + rbase;
    const int m0 = mch0*32 + row;
    const int m1 = m0 + 32;
    Gr[(size_t)m0*GW + wn0 + ln31]      = acc00[reg];
    Gr[(size_t)m0*GW + wn0 + 32 + ln31] = acc01[reg];
    Gr[(size_t)m1*GW + wn0 + ln31]      = acc10[reg];
    Gr[(size_t)m1*GW + wn0 + 32 + ln31] = acc11[reg];
  }
}

// One block per (layer, batch-row): bias + gate LN + cell update + h LN.
// Emits h fp16 hi/lo splits in MFMA-fragment-major layout (h1 fp32 only at t=SEQ).
// G reads are PLAIN (cache-resident), not nontemporal.
__global__ __launch_bounds__(256) void tick_update(
    const float* __restrict__ G,
    const float* __restrict__ b_ih0, const float* __restrict__ b_hh0,
    const float* __restrict__ b_ih1, const float* __restrict__ b_hh1,
    const float* __restrict__ g_ih0, const float* __restrict__ be_ih0,
    const float* __restrict__ g_hh0, const float* __restrict__ be_hh0,
    const float* __restrict__ g_ho0, const float* __restrict__ be_ho0,
    const float* __restrict__ g_ih1, const float* __restrict__ be_ih1,
    const float* __restrict__ g_hh1, const float* __restrict__ be_hh1,
    const float* __restrict__ g_ho1, const float* __restrict__ be_ho1,
    float* __restrict__ h0, float* __restrict__ c0,
    float* __restrict__ h1, float* __restrict__ c1,
    half_t* __restrict__ h0fh, half_t* __restrict__ h0fl,
    half_t* __restrict__ h1fh, half_t* __restrict__ h1fl, int t)
{
  const int layer = blockIdx.x >> 9;
  const int b = blockIdx.x & 511;
  if (layer==0 && t>=SEQ) return;   // layer0 active ticks 0..199
  if (layer==1 && t==0)   return;   // layer1 active ticks 1..200 (processes step t-1)

  const float *GA,*GB,*bA,*bB,*gA,*beA,*gB,*beB,*gH,*bH;
  float *cs,*hs; half_t *hfx,*lfx;
  const size_t rb = (size_t)b*GW;
  if (layer==0){
    GA = G + rb;
    GB = G + (size_t)1*BATCH*GW + rb;
    bA=b_ih0; bB=b_hh0;
    gA=g_ih0; beA=be_ih0; gB=g_hh0; beB=be_hh0; gH=g_ho0; bH=be_ho0;
    cs = c0 + b*HID; hs = nullptr; hfx = h0fh; lfx = h0fl;
  } else {
    GA = G + (size_t)2*BATCH*GW + rb;
    GB = G + (size_t)3*BATCH*GW + rb;
    bA=b_ih1; bB=b_hh1;
    gA=g_ih1; beA=be_ih1; gB=g_hh1; beB=be_hh1; gH=g_ho1; bH=be_ho1;
    cs = c1 + b*HID; hs = (t==SEQ) ? (h1 + b*HID) : nullptr; hfx = h1fh; lfx = h1fl;
  }

  const int tid = threadIdx.x;
  __shared__ float red[16];
  __shared__ __align__(16) float GS[2*GW];     // 16 KB: A-part then B-part
  __shared__ float su[HID];
  __shared__ float so[HID];

  // Pass 1 (f32x4): bias add, stage into LDS, LN stats
  float sa=0, ssa=0, sb=0, ssb=0;
  for (int i=tid*4; i<GW; i+=1024){
    f32x4 va = *(const f32x4*)(GA+i);
    va += *(const f32x4*)(bA+i);
    *(f32x4*)(GS+i) = va;
    f32x4 vb = *(const f32x4*)(GB+i);
    vb += *(const f32x4*)(bB+i);
    *(f32x4*)(GS+GW+i) = vb;
    #pragma unroll
    for (int q=0;q<4;q++){
      sa += va[q]; ssa += va[q]*va[q];
      sb += vb[q]; ssb += vb[q]*vb[q];
    }
  }
  block_reduce4(sa,ssa,sb,ssb,red);   // internal __syncthreads covers GS visibility
  const float ma = sa*(1.0f/GW);
  const float ra = rsqrtf(ssa*(1.0f/GW) - ma*ma + EPS);
  const float mb = sb*(1.0f/GW);
  const float rb_ = rsqrtf(ssb*(1.0f/GW) - mb*mb + EPS);

  // Pass 2: gates (i,f,g,o split), cell update, tanh(c) stats
  float s_u=0, s_uu=0;
  for (int j=tid;j<HID;j+=256){
    float iv = ((GS[j      ]-ma)*ra*gA[j      ]+beA[j      ]) + ((GS[GW+j      ]-mb)*rb_*gB[j      ]+beB[j      ]);
    float fv = ((GS[j+  HID]-ma)*ra*gA[j+  HID]+beA[j+  HID]) + ((GS[GW+j+  HID]-mb)*rb_*gB[j+  HID]+beB[j+  HID]);
    float gv = ((GS[j+2*HID]-ma)*ra*gA[j+2*HID]+beA[j+2*HID]) + ((GS[GW+j+2*HID]-mb)*rb_*gB[j+2*HID]+beB[j+2*HID]);
    float ov = ((GS[j+3*HID]-ma)*ra*gA[j+3*HID]+beA[j+3*HID]) + ((GS[GW+j+3*HID]-mb)*rb_*gB[j+3*HID]+beB[j+3*HID]);
    float cn = sigf(fv)*cs[j] + sigf(iv)*tanhf(gv);
    cs[j] = cn;
    float u = tanhf(cn);
    su[j] = u; so[j] = sigf(ov);
    s_u += u; s_uu += u*u;
  }
  float d3=0,d4=0;
  block_reduce4(s_u,s_uu,d3,d4,red);
  const float mu_u = s_u*(1.0f/HID);
  const float ru   = rsqrtf(s_uu*(1.0f/HID) - mu_u*mu_u + EPS);

  // Pass 3: h = sigmoid(o) * LN(tanh(c)); fp16 hi/lo in fragment layout
  const size_t fbase = ((size_t)(b>>5)*32)*512 + (size_t)(b&31)*8;
  for (int j=tid;j<HID;j+=256){
    float v = so[j] * ((su[j]-mu_u)*ru*gH[j] + bH[j]);
    if (hs) hs[j] = v;
    half_t hv = (half_t)v;
    half_t lv = (half_t)(v - (float)hv);
    const size_t fi = fbase + (size_t)(j>>4)*512 + (size_t)((j>>3)&1)*256 + (j&7);
    hfx[fi] = hv;
    lfx[fi] = lv;
  }
}

// Dense head: 512 -> 128 -> 64 -> 32 -> 1, one block per batch row
__global__ __launch_bounds__(256) void head_kernel(
    const float* __restrict__ h1,
    const float* __restrict__ Wd1, const float* __restrict__ bd1,
    const float* __restrict__ Wd2, const float* __restrict__ bd2,
    const float* __restrict__ Wd3, const float* __restrict__ bd3,
    const float* __restrict__ Wd4, const float* __restrict__ bd4,
    float* __restrict__ out)
{
  const int b = blockIdx.x;
  __shared__ float hv[HID];
  __shared__ float z1[128];
  __shared__ float z2[64];
  __shared__ float z3[32];
  const int tid = threadIdx.x;
  for (int i=tid;i<HID;i+=256) hv[i]=h1[(size_t)b*HID+i];
  __syncthreads();
  if (tid<128){
    float acc=bd1[tid]; const float* w=Wd1+(size_t)tid*512;
    for(int k=0;k<512;k++) acc+=hv[k]*w[k];
    z1[tid]=fmaxf(acc,0.f);
  }
  __syncthreads();
  if (tid<64){
    float acc=bd2[tid]; const float* w=Wd2+(size_t)tid*128;
    for(int k=0;k<128;k++) acc+=z1[k]*w[k];
    z2[tid]=fmaxf(acc,0.f);
  }
  __syncthreads();
  if (tid<32){
    float acc=bd3[tid]; const float* w=Wd3+(size_t)tid*64;
    for(int k=0;k<64;k++) acc+=z2[k]*w[k];
    z3[tid]=fmaxf(acc,0.f);
  }
  __syncthreads();
  if (tid==0){
    float acc=bd4[0];
    for(int k=0;k<32;k++) acc+=z3[k]*Wd4[k];
    out[b]=acc;
  }
}

extern "C" void kernel_launch(void* const* d_in, const int* in_sizes, int n_in,
                              void* d_out, int out_size, void* d_ws, size_t ws_size,
                              hipStream_t stream) {
  const float* x      = (const float*)d_in[0];
  const float* ln1_g  = (const float*)d_in[1];
  const float* ln1_b  = (const float*)d_in[2];
  const float* W_ih0  = (const float*)d_in[3];
  const float* b_ih0  = (const float*)d_in[4];
  const float* W_hh0  = (const float*)d_in[5];
  const float* b_hh0  = (const float*)d_in[6];
  const float* g_ih0  = (const float*)d_in[7];
  const float* be_ih0 = (const float*)d_in[8];
  const float* g_hh0  = (const float*)d_in[9];
  const float* be_hh0 = (const float*)d_in[10];
  const float* g_ho0  = (const float*)d_in[11];
  const float* be_ho0 = (const float*)d_in[12];
  const float* W_ih1  = (const float*)d_in[13];
  const float* b_ih1  = (const float*)d_in[14];
  const float* W_hh1  = (const float*)d_in[15];
  const float* b_hh1  = (const float*)d_in[16];
  const float* g_ih1  = (const float*)d_in[17];
  const float* be_ih1 = (const float*)d_in[18];
  const float* g_hh1  = (const float*)d_in[19];
  const float* be_hh1 = (const float*)d_in[20];
  const float* g_ho1  = (const float*)d_in[21];
  const float* be_ho1 = (const float*)d_in[22];
  const float* Wd1    = (const float*)d_in[23];
  const float* bd1    = (const float*)d_in[24];
  const float* Wd2    = (const float*)d_in[25];
  const float* bd2    = (const float*)d_in[26];
  const float* Wd3    = (const float*)d_in[27];
  const float* bd3    = (const float*)d_in[28];
  const float* Wd4    = (const float*)d_in[29];
  const float* bd4    = (const float*)d_in[30];
  float* out = (float*)d_out;

  // ---- workspace layout ----
  float* ws = (float*)d_ws;
  float* G  = ws;                                   // 4*512*2048 f32 = 16 MB
  float* h0 = G  + NREG*(size_t)BATCH*GW;           // fp32 state block (zeroed)
  float* c0 = h0 + (size_t)BATCH*HID;
  float* h1 = c0 + (size_t)BATCH*HID;
  float* c1 = h1 + (size_t)BATCH*HID;
  half_t* h0fh = (half_t*)(c1 + (size_t)BATCH*HID); // fp16 frag splits (zeroed)
  half_t* h0fl = h0fh + (size_t)BATCH*HID;
  half_t* h1fh = h0fl + (size_t)BATCH*HID;
  half_t* h1fl = h1fh + (size_t)BATCH*HID;
  float* mu = (float*)(h1fl + (size_t)BATCH*HID);   // 512
  float* rs = mu + BATCH;                           // 512
  half_t* Wh = (half_t*)(rs + BATCH);               // WTOT halves (packed)
  half_t* Wl = Wh + (size_t)WTOT;                   // WTOT halves (packed)
  half_t* xh = Wl + (size_t)WTOT;                   // XFRAG halves (frag-major)
  half_t* xl = xh + XFRAG;

  // zero h0,c0,h1,c1 (fp32) + 4 frag planes (fp16) in one contiguous memset
  (void)hipMemsetAsync(h0, 0, 4*(size_t)BATCH*HID*4 + 4*(size_t)BATCH*HID*2, stream);

  ln1_stats<<<BATCH, 256, 0, stream>>>(x, mu, rs);
  wsplit<<<(WTOT+255)/256, 256, 0, stream>>>(W_ih0, W_hh0, W_ih1, W_hh1, Wh, Wl);
  xprep<<<(int)((XFRAG+255)/256), 256, 0, stream>>>(x, ln1_g, ln1_b, mu, rs, xh, xl);

  for (int t = 0; t <= SEQ; ++t) {
    tick_mm64<<<dim3(256), 256, 0, stream>>>(xh, xl,
        h0fh, h0fl, h1fh, h1fl, Wh, Wl, G, t);
    tick_update<<<dim3(1024), 256, 0, stream>>>(G,
        b_ih0, b_hh0, b_ih1, b_hh1,
        g_ih0, be_ih0, g_hh0, be_hh0, g_ho0, be_ho0,
        g_ih1, be_ih1, g_hh1, be_hh1, g_ho1, be_ho1,
        h0, c0, h1, c1, h0fh, h0fl, h1fh, h1fl, t);
  }
  head_kernel<<<BATCH, 256, 0, stream>>>(h1, Wd1, bd1, Wd2, bd2, Wd3, bd3, Wd4, bd4, out);
}